// Round 1
// baseline (1120.113 us; speedup 1.0000x reference)
//
#include <hip/hip_runtime.h>

#define NN 100000
#define NE 1600000
// IN=128, HID=64, OUT=32

__global__ __launch_bounds__(256) void k_init_deg(float* deg) {
    int i = blockIdx.x * 256 + threadIdx.x;
    if (i < NN) deg[i] = 1.0f;               // self-loop
}

__global__ __launch_bounds__(256) void k_edge_deg(const int* __restrict__ dst, float* deg) {
    int e = blockIdx.x * 256 + threadIdx.x;
    if (e < NE) atomicAdd(&deg[dst[e]], 1.0f);
}

__global__ __launch_bounds__(256) void k_to_dis(float* deg) {
    int i = blockIdx.x * 256 + threadIdx.x;
    if (i < NN) deg[i] = rsqrtf(deg[i]);     // deg >= 1 always
}

// t1[N,64] = x[N,128] @ W1[128,64].  16 rows per block, W1 + x-tile in LDS.
__global__ __launch_bounds__(256) void k_gemm1(const float* __restrict__ x,
                                               const float* __restrict__ W1,
                                               float* __restrict__ t1) {
    __shared__ float Wl[128 * 64];
    __shared__ float Xl[16 * 128];
    int tid = threadIdx.x;
    for (int i = tid; i < 128 * 64; i += 256) Wl[i] = W1[i];
    long rowbase = (long)blockIdx.x * 16;    // N = 6250 * 16 exactly
    for (int i = tid; i < 16 * 128; i += 256)
        Xl[i] = x[(rowbase + (i >> 7)) * 128 + (i & 127)];
    __syncthreads();
    int col = tid & 63, rg = tid >> 6;
    float acc[4] = {0.f, 0.f, 0.f, 0.f};
    for (int k = 0; k < 128; ++k) {
        float w = Wl[k * 64 + col];
#pragma unroll
        for (int i = 0; i < 4; ++i) acc[i] += Xl[(rg * 4 + i) * 128 + k] * w;
    }
#pragma unroll
    for (int i = 0; i < 4; ++i)
        t1[(rowbase + rg * 4 + i) * 64 + col] = acc[i];
}

// agg[d,j] += dis[s]*dis[d]*feat[s,j]   (64 dims, wave = one edge)
__global__ __launch_bounds__(256) void k_scatter1(const float* __restrict__ feat,
                                                  const int* __restrict__ src,
                                                  const int* __restrict__ dst,
                                                  const float* __restrict__ dis,
                                                  float* __restrict__ agg) {
    long t = (long)blockIdx.x * 256 + threadIdx.x;
    long e = t >> 6; int j = (int)(t & 63);
    if (e >= NE) return;
    int s = src[e], d = dst[e];
    float nrm = dis[s] * dis[d];
    atomicAdd(&agg[(long)d * 64 + j], nrm * feat[(long)s * 64 + j]);
}

// h = normalize(relu(agg + dis^2 * t1 + b1)); in-place on agg.  Wave per row.
__global__ __launch_bounds__(256) void k_relu_norm(const float* __restrict__ t1,
                                                   const float* __restrict__ dis,
                                                   const float* __restrict__ b1,
                                                   float* __restrict__ h) {
    long t = (long)blockIdx.x * 256 + threadIdx.x;
    long v = t >> 6; int j = (int)(t & 63);
    if (v >= NN) return;
    float dv = dis[v];
    float val = h[v * 64 + j] + dv * dv * t1[v * 64 + j] + b1[j];
    val = fmaxf(val, 0.0f);
    float ss = val * val;
#pragma unroll
    for (int m = 1; m < 64; m <<= 1) ss += __shfl_xor(ss, m);
    float scale = 1.0f / fmaxf(sqrtf(ss), 1e-12f);
    h[v * 64 + j] = val * scale;
}

// t2[N,64] = h[N,64] @ [Wmu | Wls]  (each [64,32])
__global__ __launch_bounds__(256) void k_gemm2(const float* __restrict__ h,
                                               const float* __restrict__ Wmu,
                                               const float* __restrict__ Wls,
                                               float* __restrict__ t2) {
    __shared__ float Wl[64 * 64];
    __shared__ float Hl[16 * 64];
    int tid = threadIdx.x;
    for (int i = tid; i < 64 * 64; i += 256) {
        int k = i >> 6, j = i & 63;
        Wl[i] = (j < 32) ? Wmu[k * 32 + j] : Wls[k * 32 + j - 32];
    }
    long rowbase = (long)blockIdx.x * 16;
    for (int i = tid; i < 16 * 64; i += 256) Hl[i] = h[rowbase * 64 + i];
    __syncthreads();
    int col = tid & 63, rg = tid >> 6;
    float acc[4] = {0.f, 0.f, 0.f, 0.f};
    for (int k = 0; k < 64; ++k) {
        float w = Wl[k * 64 + col];
#pragma unroll
        for (int i = 0; i < 4; ++i) acc[i] += Hl[(rg * 4 + i) * 64 + k] * w;
    }
#pragma unroll
    for (int i = 0; i < 4; ++i)
        t2[(rowbase + rg * 4 + i) * 64 + col] = acc[i];
}

// scatter layer-2 aggregation straight into d_out's mu / logstd regions
__global__ __launch_bounds__(256) void k_scatter2(const float* __restrict__ feat,
                                                  const int* __restrict__ src,
                                                  const int* __restrict__ dst,
                                                  const float* __restrict__ dis,
                                                  float* __restrict__ mu,
                                                  float* __restrict__ ls) {
    long t = (long)blockIdx.x * 256 + threadIdx.x;
    long e = t >> 6; int j = (int)(t & 63);
    if (e >= NE) return;
    int s = src[e], d = dst[e];
    float nrm = dis[s] * dis[d];
    float val = nrm * feat[(long)s * 64 + j];
    if (j < 32) atomicAdd(&mu[(long)d * 32 + j], val);
    else        atomicAdd(&ls[(long)d * 32 + j - 32], val);
}

// bias + self-loop + reparametrize.  Wave per node; lanes 0..31 = mu dims,
// lanes 32..63 = logstd dims; shfl_xor(32) crosses them for z.
__global__ __launch_bounds__(256) void k_finalize(const float* __restrict__ t2,
                                                  const float* __restrict__ dis,
                                                  const float* __restrict__ bmu,
                                                  const float* __restrict__ bls,
                                                  const float* __restrict__ eps,
                                                  float* __restrict__ mu,
                                                  float* __restrict__ ls,
                                                  float* __restrict__ z) {
    long t = (long)blockIdx.x * 256 + threadIdx.x;
    long v = t >> 6; int j = (int)(t & 63);
    if (v >= NN) return;
    float dv = dis[v];
    float self = dv * dv * t2[v * 64 + j];
    float val;
    if (j < 32) val = mu[v * 32 + j] + self + bmu[j];
    else        val = ls[v * 32 + j - 32] + self + bls[j - 32];
    float other = __shfl_xor(val, 32);
    if (j < 32) {
        mu[v * 32 + j] = val;
        float lc = fminf(fmaxf(other, -10.0f), 10.0f);
        z[v * 32 + j] = val + eps[v * 32 + j] * expf(lc);
    } else {
        ls[v * 32 + j - 32] = val;
    }
}

// adj_pred[e] = sigmoid(<z[src], z[dst]>), 32 lanes per edge
__global__ __launch_bounds__(256) void k_decode(const float* __restrict__ z,
                                                const int* __restrict__ src,
                                                const int* __restrict__ dst,
                                                float* __restrict__ out) {
    long t = (long)blockIdx.x * 256 + threadIdx.x;
    long e = t >> 5; int j = (int)(t & 31);
    if (e >= NE) return;
    int s = src[e], d = dst[e];
    float p = z[(long)s * 32 + j] * z[(long)d * 32 + j];
#pragma unroll
    for (int m = 1; m < 32; m <<= 1) p += __shfl_xor(p, m);
    if (j == 0) out[e] = 1.0f / (1.0f + expf(-p));
}

extern "C" void kernel_launch(void* const* d_in, const int* in_sizes, int n_in,
                              void* d_out, int out_size, void* d_ws, size_t ws_size,
                              hipStream_t stream) {
    const float* x   = (const float*)d_in[0];
    const int*   ei  = (const int*)d_in[1];
    const float* eps = (const float*)d_in[2];
    const float* W1  = (const float*)d_in[3];
    const float* b1  = (const float*)d_in[4];
    const float* Wmu = (const float*)d_in[5];
    const float* bmu = (const float*)d_in[6];
    const float* Wls = (const float*)d_in[7];
    const float* bls = (const float*)d_in[8];
    const int* src = ei;        // edge_index[0]
    const int* dst = ei + NE;   // edge_index[1]

    float* out = (float*)d_out;
    float* adj = out;                       // [E]
    float* mu  = out + NE;                  // [N,32]
    float* ls  = mu + (long)NN * 32;        // [N,32]

    float* dis = (float*)d_ws;              // [N]
    float* t1  = dis + NN;                  // [N,64], reused as t2
    float* agg = t1 + (long)NN * 64;        // [N,64], becomes h in-place
    float* z   = agg + (long)NN * 64;       // [N,32]

    hipMemsetAsync(agg, 0, (size_t)NN * 64 * sizeof(float), stream);
    hipMemsetAsync(mu,  0, (size_t)NN * 64 * sizeof(float), stream); // mu+ls contiguous

    const int B = 256;
    k_init_deg<<<(NN + B - 1) / B, B, 0, stream>>>(dis);
    k_edge_deg<<<(NE + B - 1) / B, B, 0, stream>>>(dst, dis);
    k_to_dis<<<(NN + B - 1) / B, B, 0, stream>>>(dis);

    k_gemm1<<<NN / 16, B, 0, stream>>>(x, W1, t1);
    k_scatter1<<<(long)NE * 64 / B, B, 0, stream>>>(t1, src, dst, dis, agg);
    k_relu_norm<<<(long)NN * 64 / B, B, 0, stream>>>(t1, dis, b1, agg);

    k_gemm2<<<NN / 16, B, 0, stream>>>(agg, Wmu, Wls, t1);
    k_scatter2<<<(long)NE * 64 / B, B, 0, stream>>>(t1, src, dst, dis, mu, ls);
    k_finalize<<<(long)NN * 64 / B, B, 0, stream>>>(t1, dis, bmu, bls, eps, mu, ls, z);

    k_decode<<<(long)NE * 32 / B, B, 0, stream>>>(z, src, dst, adj);
}

// Round 2
// 635.294 us; speedup vs baseline: 1.7631x; 1.7631x over previous
//
#include <hip/hip_runtime.h>

#define NN 100000
#define NE 1600000
// IN=128, HID=64, OUT=32

// ---------------- degree / CSR build ----------------

__global__ __launch_bounds__(256) void k_hist(const int* __restrict__ dst, int* __restrict__ hist) {
    int e = blockIdx.x * 256 + threadIdx.x;
    if (e < NE) atomicAdd(&hist[dst[e]], 1);
}

__global__ __launch_bounds__(256) void k_dis(const int* __restrict__ hist, float* __restrict__ dis) {
    int i = blockIdx.x * 256 + threadIdx.x;
    if (i < NN) dis[i] = rsqrtf((float)(1 + hist[i]));   // +1 self-loop
}

// per-block exclusive scan of hist -> row_ptr(local), block total -> partial[b]
__global__ __launch_bounds__(256) void k_scan1(const int* __restrict__ hist,
                                               int* __restrict__ row_ptr,
                                               int* __restrict__ partial) {
    __shared__ int buf[256];
    int tid = threadIdx.x;
    int i = blockIdx.x * 256 + tid;
    int v = (i < NN) ? hist[i] : 0;
    buf[tid] = v;
    __syncthreads();
    for (int off = 1; off < 256; off <<= 1) {
        int t = (tid >= off) ? buf[tid - off] : 0;
        __syncthreads();
        buf[tid] += t;
        __syncthreads();
    }
    if (i < NN) row_ptr[i] = buf[tid] - v;     // exclusive within block
    if (tid == 255) partial[blockIdx.x] = buf[255];
}

// exclusive scan of 391 block partials (one block of 512)
__global__ __launch_bounds__(512) void k_scan2(int* __restrict__ partial, int nb) {
    __shared__ int buf[512];
    int tid = threadIdx.x;
    int v = (tid < nb) ? partial[tid] : 0;
    buf[tid] = v;
    __syncthreads();
    for (int off = 1; off < 512; off <<= 1) {
        int t = (tid >= off) ? buf[tid - off] : 0;
        __syncthreads();
        buf[tid] += t;
        __syncthreads();
    }
    partial[tid < 512 ? tid : 0] = buf[tid] - v;   // exclusive
}

// add block offsets; init cursor; write row_ptr[NN]
__global__ __launch_bounds__(256) void k_scan3(int* __restrict__ row_ptr,
                                               const int* __restrict__ partial,
                                               int* __restrict__ cursor) {
    int i = blockIdx.x * 256 + threadIdx.x;
    if (i < NN) {
        int v = row_ptr[i] + partial[blockIdx.x];
        row_ptr[i] = v;
        cursor[i] = v;
    }
    if (i == 0) row_ptr[NN] = NE;
}

__global__ __launch_bounds__(256) void k_fill(const int* __restrict__ src,
                                              const int* __restrict__ dst,
                                              int* __restrict__ cursor,
                                              int* __restrict__ csr_src) {
    int e = blockIdx.x * 256 + threadIdx.x;
    if (e >= NE) return;
    int d = dst[e];
    int pos = atomicAdd(&cursor[d], 1);
    csr_src[pos] = src[e];
}

// ---------------- dense transforms ----------------

// t1[N,64] = x[N,128] @ W1[128,64].  16 rows per block, W1 + x-tile in LDS.
__global__ __launch_bounds__(256) void k_gemm1(const float* __restrict__ x,
                                               const float* __restrict__ W1,
                                               float* __restrict__ t1) {
    __shared__ float Wl[128 * 64];
    __shared__ float Xl[16 * 128];
    int tid = threadIdx.x;
    const float4* W4 = (const float4*)W1;
    float4* Wl4 = (float4*)Wl;
    for (int i = tid; i < 128 * 16; i += 256) Wl4[i] = W4[i];
    long rowbase = (long)blockIdx.x * 16;      // N = 6250 * 16 exactly
    const float4* X4 = (const float4*)(x + rowbase * 128);
    float4* Xl4 = (float4*)Xl;
    for (int i = tid; i < 16 * 32; i += 256) Xl4[i] = X4[i];
    __syncthreads();
    int col = tid & 63, rg = tid >> 6;
    float acc[4] = {0.f, 0.f, 0.f, 0.f};
    for (int k = 0; k < 128; ++k) {
        float w = Wl[k * 64 + col];
#pragma unroll
        for (int i = 0; i < 4; ++i) acc[i] += Xl[(rg * 4 + i) * 128 + k] * w;
    }
#pragma unroll
    for (int i = 0; i < 4; ++i)
        t1[(rowbase + rg * 4 + i) * 64 + col] = acc[i];
}

// t2[N,64] = h[N,64] @ [Wmu | Wls]  (each [64,32])
__global__ __launch_bounds__(256) void k_gemm2(const float* __restrict__ h,
                                               const float* __restrict__ Wmu,
                                               const float* __restrict__ Wls,
                                               float* __restrict__ t2) {
    __shared__ float Wl[64 * 64];
    __shared__ float Hl[16 * 64];
    int tid = threadIdx.x;
    for (int i = tid; i < 64 * 64; i += 256) {
        int k = i >> 6, j = i & 63;
        Wl[i] = (j < 32) ? Wmu[k * 32 + j] : Wls[k * 32 + j - 32];
    }
    long rowbase = (long)blockIdx.x * 16;
    const float4* H4 = (const float4*)(h + rowbase * 64);
    float4* Hl4 = (float4*)Hl;
    for (int i = tid; i < 16 * 16; i += 256) Hl4[i] = H4[i];
    __syncthreads();
    int col = tid & 63, rg = tid >> 6;
    float acc[4] = {0.f, 0.f, 0.f, 0.f};
    for (int k = 0; k < 64; ++k) {
        float w = Wl[k * 64 + col];
#pragma unroll
        for (int i = 0; i < 4; ++i) acc[i] += Hl[(rg * 4 + i) * 64 + k] * w;
    }
#pragma unroll
    for (int i = 0; i < 4; ++i)
        t2[(rowbase + rg * 4 + i) * 64 + col] = acc[i];
}

// ---------------- fused gather-aggregations ----------------

// h[v] = l2normalize(relu(dis[v]*(sum_s dis[s]*t1[s] + dis[v]*t1[v]) + b1))
__global__ __launch_bounds__(256) void k_agg1(const float* __restrict__ t1,
                                              const int* __restrict__ row_ptr,
                                              const int* __restrict__ csr_src,
                                              const float* __restrict__ dis,
                                              const float* __restrict__ b1,
                                              float* __restrict__ h) {
    long t = (long)blockIdx.x * 256 + threadIdx.x;
    int v = (int)(t >> 6), j = (int)(t & 63);
    if (v >= NN) return;
    int beg = row_ptr[v], end = row_ptr[v + 1];
    float acc = 0.f;
    int i = beg;
    for (; i + 4 <= end; i += 4) {
        int s0 = csr_src[i], s1 = csr_src[i + 1], s2 = csr_src[i + 2], s3 = csr_src[i + 3];
        float a0 = dis[s0] * t1[s0 * 64 + j];
        float a1 = dis[s1] * t1[s1 * 64 + j];
        float a2 = dis[s2] * t1[s2 * 64 + j];
        float a3 = dis[s3] * t1[s3 * 64 + j];
        acc += (a0 + a1) + (a2 + a3);
    }
    for (; i < end; ++i) {
        int s = csr_src[i];
        acc += dis[s] * t1[s * 64 + j];
    }
    float dv = dis[v];
    float val = dv * (acc + dv * t1[v * 64 + j]) + b1[j];
    val = fmaxf(val, 0.0f);
    float ss = val * val;
#pragma unroll
    for (int m = 1; m < 64; m <<= 1) ss += __shfl_xor(ss, m);
    float scale = 1.0f / fmaxf(sqrtf(ss), 1e-12f);
    h[v * 64 + j] = val * scale;
}

// layer-2 aggregation fused with bias + reparametrize; writes mu, ls, z
__global__ __launch_bounds__(256) void k_agg2(const float* __restrict__ t2,
                                              const int* __restrict__ row_ptr,
                                              const int* __restrict__ csr_src,
                                              const float* __restrict__ dis,
                                              const float* __restrict__ bmu,
                                              const float* __restrict__ bls,
                                              const float* __restrict__ eps,
                                              float* __restrict__ mu,
                                              float* __restrict__ ls,
                                              float* __restrict__ z) {
    long t = (long)blockIdx.x * 256 + threadIdx.x;
    int v = (int)(t >> 6), j = (int)(t & 63);
    if (v >= NN) return;
    int beg = row_ptr[v], end = row_ptr[v + 1];
    float acc = 0.f;
    int i = beg;
    for (; i + 4 <= end; i += 4) {
        int s0 = csr_src[i], s1 = csr_src[i + 1], s2 = csr_src[i + 2], s3 = csr_src[i + 3];
        float a0 = dis[s0] * t2[s0 * 64 + j];
        float a1 = dis[s1] * t2[s1 * 64 + j];
        float a2 = dis[s2] * t2[s2 * 64 + j];
        float a3 = dis[s3] * t2[s3 * 64 + j];
        acc += (a0 + a1) + (a2 + a3);
    }
    for (; i < end; ++i) {
        int s = csr_src[i];
        acc += dis[s] * t2[s * 64 + j];
    }
    float dv = dis[v];
    float val = dv * (acc + dv * t2[v * 64 + j]) + ((j < 32) ? bmu[j] : bls[j - 32]);
    float other = __shfl_xor(val, 32);
    if (j < 32) {
        mu[v * 32 + j] = val;
        float lc = fminf(fmaxf(other, -10.0f), 10.0f);
        z[v * 32 + j] = val + eps[v * 32 + j] * expf(lc);
    } else {
        ls[v * 32 + j - 32] = val;
    }
}

// adj_pred[e] = sigmoid(<z[src], z[dst]>), 8 lanes per edge, float4 loads
__global__ __launch_bounds__(256) void k_decode(const float* __restrict__ z,
                                                const int* __restrict__ src,
                                                const int* __restrict__ dst,
                                                float* __restrict__ out) {
    long t = (long)blockIdx.x * 256 + threadIdx.x;
    long e = t >> 3; int l = (int)(t & 7);
    if (e >= NE) return;
    int s = src[e], d = dst[e];
    const float4* z4 = (const float4*)z;
    float4 a = z4[s * 8 + l];
    float4 b = z4[d * 8 + l];
    float p = a.x * b.x + a.y * b.y + a.z * b.z + a.w * b.w;
    p += __shfl_xor(p, 1);
    p += __shfl_xor(p, 2);
    p += __shfl_xor(p, 4);
    if (l == 0) out[e] = 1.0f / (1.0f + expf(-p));
}

extern "C" void kernel_launch(void* const* d_in, const int* in_sizes, int n_in,
                              void* d_out, int out_size, void* d_ws, size_t ws_size,
                              hipStream_t stream) {
    const float* x   = (const float*)d_in[0];
    const int*   ei  = (const int*)d_in[1];
    const float* eps = (const float*)d_in[2];
    const float* W1  = (const float*)d_in[3];
    const float* b1  = (const float*)d_in[4];
    const float* Wmu = (const float*)d_in[5];
    const float* bmu = (const float*)d_in[6];
    const float* Wls = (const float*)d_in[7];
    const float* bls = (const float*)d_in[8];
    const int* src = ei;        // edge_index[0]
    const int* dst = ei + NE;   // edge_index[1]

    float* out = (float*)d_out;
    float* adj = out;                       // [E]
    float* mu  = out + NE;                  // [N,32]
    float* ls  = mu + (long)NN * 32;        // [N,32]

    // workspace layout (16B-alignment preserved: int block padded to mult of 4)
    float* dis     = (float*)d_ws;              // NN (100000, mult of 4)
    int*   row_ptr = (int*)(dis + NN);          // NN+1, padded to 100004
    int*   cursor  = row_ptr + 100004;          // NN (hist, then fill cursor)
    int*   partial = cursor + NN;               // 512
    int*   csr_src = partial + 512;             // NE
    float* t       = (float*)(csr_src + NE);    // NN*64  (t1 then t2)
    float* h       = t + (long)NN * 64;         // NN*64
    float* z       = h + (long)NN * 64;         // NN*32

    const int B = 256;
    const int NB_N = (NN + B - 1) / B;          // 391
    const int NB_E = (NE + B - 1) / B;          // 6250

    hipMemsetAsync(cursor, 0, (size_t)NN * sizeof(int), stream);

    // CSR build + dis
    k_hist <<<NB_E, B, 0, stream>>>(dst, cursor);
    k_dis  <<<NB_N, B, 0, stream>>>(cursor, dis);
    k_scan1<<<NB_N, B, 0, stream>>>(cursor, row_ptr, partial);
    k_scan2<<<1, 512, 0, stream>>>(partial, NB_N);
    k_scan3<<<NB_N, B, 0, stream>>>(row_ptr, partial, cursor);
    k_fill <<<NB_E, B, 0, stream>>>(src, dst, cursor, csr_src);

    // layer 1
    k_gemm1<<<NN / 16, B, 0, stream>>>(x, W1, t);
    k_agg1 <<<(int)(((long)NN * 64 + B - 1) / B), B, 0, stream>>>(t, row_ptr, csr_src, dis, b1, h);

    // layer 2
    k_gemm2<<<NN / 16, B, 0, stream>>>(h, Wmu, Wls, t);
    k_agg2 <<<(int)(((long)NN * 64 + B - 1) / B), B, 0, stream>>>(t, row_ptr, csr_src, dis,
                                                                  bmu, bls, eps, mu, ls, z);

    // decode
    k_decode<<<(int)(((long)NE * 8 + B - 1) / B), B, 0, stream>>>(z, src, dst, adj);
}